// Round 5
// baseline (633.934 us; speedup 1.0000x reference)
//
#include <hip/hip_runtime.h>
#include <stdint.h>

#define H 256
#define NATOMS 100000
#define MB 32
#define NT (NATOMS / MB)   // 3125 tiles
#define PGRID 256          // persistent blocks (1 per CU)

typedef float floatx4 __attribute__((ext_vector_type(4)));
typedef short short8 __attribute__((ext_vector_type(8)));
typedef short short4v __attribute__((ext_vector_type(4)));

// lgkm-only barrier: never drains vmcnt (staging loads / output stores stay in flight)
#define BAR() do { asm volatile("s_waitcnt lgkmcnt(0)\n\ts_barrier" ::: "memory"); __builtin_amdgcn_sched_barrier(0); } while (0)

__device__ __forceinline__ unsigned short f2bf(float x) {
    union { float f; uint32_t u; } c; c.f = x;
    return (unsigned short)((c.u + 0x7FFFu + ((c.u >> 16) & 1u)) >> 16);
}
__device__ __forceinline__ float bf2f(unsigned short h) {
    union { uint32_t u; float f; } c; c.u = ((uint32_t)h) << 16; return c.f;
}

// ---------------------------------------------------------------------------
// Pack weights (f32 [K][N] row-major) into bf16 MFMA-B-fragment order.
// frag fl = nb*(K/32)+kb; lane l holds W[kb*32+(l>>4)*8+e][nb*16+(l&15)].
// ws layout (bf16 elems): U@0, V@65536, W1@131072, W2@262144 (896KB total).
// ---------------------------------------------------------------------------
__global__ void pack_weights(const float* __restrict__ U_W, const float* __restrict__ V_W,
                             const float* __restrict__ W1, const float* __restrict__ W2,
                             unsigned short* __restrict__ P) {
    int gtid = blockIdx.x * 256 + threadIdx.x;
    int fid = gtid >> 6, l = gtid & 63;
    const float* src; int K, N, fl; unsigned short* dst;
    if (fid < 128)      { src = U_W; K = 256; N = 256; fl = fid;       dst = P; }
    else if (fid < 256) { src = V_W; K = 256; N = 256; fl = fid - 128; dst = P + 65536; }
    else if (fid < 512) { src = W1;  K = 512; N = 256; fl = fid - 256; dst = P + 131072; }
    else                { src = W2;  K = 256; N = 768; fl = fid - 512; dst = P + 262144; }
    int kbc = K >> 5;
    int nb = fl / kbc, kb = fl - nb * kbc;
    int k0 = kb * 32 + ((l >> 4) << 3);
    int n0 = nb * 16 + (l & 15);
    short8 outv;
#pragma unroll
    for (int e = 0; e < 8; e++) outv[e] = (short)f2bf(src[(size_t)(k0 + e) * N + n0]);
    *(short8*)(dst + (size_t)fl * 512 + l * 8) = outv;
}

// ---------------------------------------------------------------------------
// Persistent fused PaiNN mixing. Grid = 256 blocks x 1024 thr (16 waves).
// Each block loops tiles t = bid, bid+256, ... (tile = 32 atoms).
// LDS frags are 1KB, MFMA-A-linear with kpos-XOR swizzle:
//   element (row a15, k): kpos=(k>>3)&3, byte = kpos*256 + ((a15^kpos)*16) + (k&7)*2
//   lane read offset: loff = (l>>4)*256 + (((l&15)^(l>>4))*16)
// VF[2]: v-tile frags [g][d*8+ks] (2x24 frags, dbuf). LNf: s_normed [g][ks] (16).
// NMf: Vv_norm then hid (16). muS: per-atom (mu, sigma).
// Wave w owns output cols [16w,16w+16). Pipeline per tile:
//  p1(VF[pb]) | normw BAR issue_v(tn) p2 BAR hidw,write_v(pb^1) BAR p3
//  issue_s(tn) epi(LNf,VF[pb],regs) BAR LN(tn)   -- all BARs lgkm-only.
// ---------------------------------------------------------------------------
__global__ __launch_bounds__(1024) void painn_main(
    const float* __restrict__ s, const float* __restrict__ v,
    const float* __restrict__ gamma, const float* __restrict__ beta,
    const float* __restrict__ b1, const float* __restrict__ b2,
    const unsigned short* __restrict__ P,
    float* __restrict__ s_out, float* __restrict__ v_out) {

    __shared__ unsigned short VF[2][24576];  // 2 x 48KB
    __shared__ unsigned short LNf[8192];     // 16KB
    __shared__ unsigned short NMf[8192];     // 16KB
    __shared__ float muS[64];                // 32 atoms x (mu, sigma)

    const int tid = threadIdx.x;
    const int w = tid >> 6, l = tid & 63;
    const int l15 = l & 15, lhi = l >> 4;
    const int loff = (lhi << 8) | ((l15 ^ lhi) << 4);
    const int c = (w << 4) | l15;                 // this thread's column (fixed)
    const int kposN = ((w << 1) | (l15 >> 3)) & 3;
    const int fragN = w >> 1;                      // (c>>5)
    const int ebyt = (kposN << 8) | ((c & 7) << 1);
    const float gc = gamma[c], bc = beta[c];
    const float rgc = 1.0f / gc;
    const float b1c = b1[c];
    const float bss = b2[c], bsv = b2[256 + c], bvv = b2[512 + c];
    const int aLN = tid >> 5, lg = tid & 31;       // LN mapping: 32 lanes/atom

    // staging map for v: 3 b128 writes/thread (pairs of float4)
    int sfrg[3], sbyt[3]; size_t svgi[3];
#pragma unroll
    for (int i = 0; i < 3; i++) {
        int flat2 = i * 1024 + tid;
        int a = flat2 / 96, rem = flat2 - a * 96;
        int d = rem >> 5, c8 = rem & 31;
        int ks = c8 >> 2, kp = c8 & 3;
        int g = a >> 4, a15 = a & 15;
        sfrg[i] = g * 24 + d * 8 + ks;
        sbyt[i] = (kp << 8) | ((a15 ^ kp) << 4);
        svgi[i] = ((size_t)a * 3 + d) * 64 + c8 * 2;
    }

    floatx4 vr[6], sr[2];

    auto issue_v = [&](int t) {
        const floatx4* vsrc = (const floatx4*)v + (size_t)t * (MB * 3 * 64);
#pragma unroll
        for (int i = 0; i < 3; i++) { vr[2 * i] = vsrc[svgi[i]]; vr[2 * i + 1] = vsrc[svgi[i] + 1]; }
    };
    auto write_v = [&](int pbuf) {
#pragma unroll
        for (int i = 0; i < 3; i++) {
            short8 pk;
#pragma unroll
            for (int j = 0; j < 4; j++) { pk[j] = (short)f2bf(vr[2 * i][j]); pk[4 + j] = (short)f2bf(vr[2 * i + 1][j]); }
            *(short8*)((char*)VF[pbuf] + (sfrg[i] << 10) + sbyt[i]) = pk;
        }
    };
    auto issue_s = [&](int t) {
        const floatx4* srow = (const floatx4*)(s + ((size_t)t * MB + aLN) * H);
        sr[0] = srow[lg]; sr[1] = srow[lg + 32];
    };
    auto do_ln = [&]() {
        float sum = 0.f, sq = 0.f;
#pragma unroll
        for (int i = 0; i < 2; i++)
#pragma unroll
            for (int j = 0; j < 4; j++) { sum += sr[i][j]; sq += sr[i][j] * sr[i][j]; }
#pragma unroll
        for (int m = 1; m < 32; m <<= 1) { sum += __shfl_xor(sum, m); sq += __shfl_xor(sq, m); }
        float mu = sum * (1.f / 256.f);
        float var = sq * (1.f / 256.f) - mu * mu;
        float sg = sqrtf(var + 1e-5f);
        float rs = 1.0f / sg;
        if (lg == 0) { muS[aLN * 2] = mu; muS[aLN * 2 + 1] = sg; }
        int g = aLN >> 4, a15 = aLN & 15;
#pragma unroll
        for (int i = 0; i < 2; i++) {
            int chunk = lg + (i << 5);
            floatx4 g4 = *(const floatx4*)(gamma + chunk * 4);
            floatx4 be4 = *(const floatx4*)(beta + chunk * 4);
            short4v pk;
#pragma unroll
            for (int j = 0; j < 4; j++) pk[j] = (short)f2bf((sr[i][j] - mu) * rs * g4[j] + be4[j]);
            int ks2 = chunk >> 3, kp = (chunk >> 1) & 3, low = chunk & 1;
            int bo = ((g * 8 + ks2) << 10) + (kp << 8) + ((a15 ^ kp) << 4) + low * 8;
            *(short4v*)((char*)LNf + bo) = pk;
        }
    };

    // ---- prologue: stage tile t0 ----
    const int t0 = blockIdx.x;
    issue_v(t0); issue_s(t0);
    write_v(0);
    do_ln();
    BAR();

    int pb = 0;
    for (int t = t0; t < NT; t += PGRID) {
        const int tn = (t + PGRID < NT) ? (t + PGRID) : t;
        const int atom0 = t * MB;

        // ---- phase 1: Uv & Vv ----
        floatx4 accU[3][2], accV[3][2];
#pragma unroll
        for (int d = 0; d < 3; d++)
#pragma unroll
            for (int g = 0; g < 2; g++) { accU[d][g] = (floatx4)0.f; accV[d][g] = (floatx4)0.f; }
        {
            const short8* PU = (const short8*)P;
            const short8* PV = (const short8*)(P + 65536);
            short8 bU[2], bV[2];
            bU[0] = PU[(size_t)(w * 8) * 64 + l];
            bV[0] = PV[(size_t)(w * 8) * 64 + l];
#pragma unroll
            for (int ks = 0; ks < 8; ks++) {
                int cur = ks & 1, nxt = cur ^ 1;
                if (ks < 7) {
                    bU[nxt] = PU[(size_t)(w * 8 + ks + 1) * 64 + l];
                    bV[nxt] = PV[(size_t)(w * 8 + ks + 1) * 64 + l];
                }
                __builtin_amdgcn_s_setprio(1);
#pragma unroll
                for (int d = 0; d < 3; d++) {
                    short8 a0 = *(const short8*)((const char*)VF[pb] + ((d * 8 + ks) << 10) + loff);
                    short8 a1 = *(const short8*)((const char*)VF[pb] + ((24 + d * 8 + ks) << 10) + loff);
                    accU[d][0] = __builtin_amdgcn_mfma_f32_16x16x32_bf16(a0, bU[cur], accU[d][0], 0, 0, 0);
                    accV[d][0] = __builtin_amdgcn_mfma_f32_16x16x32_bf16(a0, bV[cur], accV[d][0], 0, 0, 0);
                    accU[d][1] = __builtin_amdgcn_mfma_f32_16x16x32_bf16(a1, bU[cur], accU[d][1], 0, 0, 0);
                    accV[d][1] = __builtin_amdgcn_mfma_f32_16x16x32_bf16(a1, bV[cur], accV[d][1], 0, 0, 0);
                }
                __builtin_amdgcn_s_setprio(0);
            }
        }

        // ---- dot_uv (regs) + ||Vv|| -> NMf ----
        float dotv[2][4];
#pragma unroll
        for (int g = 0; g < 2; g++)
#pragma unroll
            for (int j = 0; j < 4; j++) {
                float du = accU[0][g][j] * accV[0][g][j] + accU[1][g][j] * accV[1][g][j]
                         + accU[2][g][j] * accV[2][g][j];
                dotv[g][j] = du;
                float nv = sqrtf(accV[0][g][j] * accV[0][g][j] + accV[1][g][j] * accV[1][g][j]
                               + accV[2][g][j] * accV[2][g][j] + 1e-8f);
                int a15 = (lhi << 2) + j;
                int bo = ((g * 8 + fragN) << 10) + ((a15 ^ kposN) << 4) + ebyt;
                *(unsigned short*)((char*)NMf + bo) = f2bf(nv);
            }

        BAR();  // B2: norm visible; phase2 may read LNf+NMf

        issue_v(tn);   // HBM loads for next tile hide under phase 2

        // ---- phase 2: hid = silu(ctx_in @ W1 + b1) ----
        floatx4 acc2[2];
        acc2[0] = (floatx4)0.f; acc2[1] = (floatx4)0.f;
        {
            const short8* PW1 = (const short8*)(P + 131072);
            short8 bw[2];
            bw[0] = PW1[(size_t)(w * 16) * 64 + l];
#pragma unroll
            for (int ks2 = 0; ks2 < 16; ks2++) {
                int cur = ks2 & 1, nxt = cur ^ 1;
                if (ks2 < 15) bw[nxt] = PW1[(size_t)(w * 16 + ks2 + 1) * 64 + l];
                const char* base0 = (ks2 < 8) ? ((const char*)LNf + ((ks2) << 10))
                                              : ((const char*)NMf + ((ks2 - 8) << 10));
                const char* base1 = (ks2 < 8) ? ((const char*)LNf + ((8 + ks2) << 10))
                                              : ((const char*)NMf + ((ks2) << 10));
                short8 af0 = *(const short8*)(base0 + loff);
                short8 af1 = *(const short8*)(base1 + loff);
                __builtin_amdgcn_s_setprio(1);
                acc2[0] = __builtin_amdgcn_mfma_f32_16x16x32_bf16(af0, bw[cur], acc2[0], 0, 0, 0);
                acc2[1] = __builtin_amdgcn_mfma_f32_16x16x32_bf16(af1, bw[cur], acc2[1], 0, 0, 0);
                __builtin_amdgcn_s_setprio(0);
            }
        }

        BAR();  // B2.5: phase-2 LDS reads done -> NMf reusable as hid

        // hid writes + stage next v-tile into VF[pb^1]
#pragma unroll
        for (int g = 0; g < 2; g++)
#pragma unroll
            for (int j = 0; j < 4; j++) {
                int a15 = (lhi << 2) + j;
                float x = acc2[g][j] + b1c;
                float hh = x / (1.f + __expf(-x));
                int bo = ((g * 8 + fragN) << 10) + ((a15 ^ kposN) << 4) + ebyt;
                *(unsigned short*)((char*)NMf + bo) = f2bf(hh);
            }
        write_v(pb ^ 1);

        BAR();  // B3: hid visible

        // ---- phase 3: ctx = hid @ W2 + b2 (3 segments, matched 16-col strips) ----
        floatx4 acc3[3][2];
#pragma unroll
        for (int sg2 = 0; sg2 < 3; sg2++)
#pragma unroll
            for (int g = 0; g < 2; g++) acc3[sg2][g] = (floatx4)0.f;
        {
            const short8* PW2 = (const short8*)(P + 262144);
            short8 bw[2][3];
#pragma unroll
            for (int sg2 = 0; sg2 < 3; sg2++)
                bw[0][sg2] = PW2[(size_t)((sg2 * 16 + w) * 8) * 64 + l];
#pragma unroll
            for (int ks3 = 0; ks3 < 8; ks3++) {
                int cur = ks3 & 1, nxt = cur ^ 1;
                if (ks3 < 7) {
#pragma unroll
                    for (int sg2 = 0; sg2 < 3; sg2++)
                        bw[nxt][sg2] = PW2[(size_t)((sg2 * 16 + w) * 8 + ks3 + 1) * 64 + l];
                }
#pragma unroll
                for (int g = 0; g < 2; g++) {
                    short8 af = *(const short8*)((const char*)NMf + ((g * 8 + ks3) << 10) + loff);
                    __builtin_amdgcn_s_setprio(1);
#pragma unroll
                    for (int sg2 = 0; sg2 < 3; sg2++)
                        acc3[sg2][g] = __builtin_amdgcn_mfma_f32_16x16x32_bf16(af, bw[cur][sg2], acc3[sg2][g], 0, 0, 0);
                    __builtin_amdgcn_s_setprio(0);
                }
            }
        }

        issue_s(tn);   // s loads for next tile hide under epilogue

        // ---- epilogue: all inputs from regs/LDS ----
#pragma unroll
        for (int g = 0; g < 2; g++)
#pragma unroll
            for (int j = 0; j < 4; j++) {
                int a15 = (lhi << 2) + j;
                int a = (g << 4) + a15;
                float mu = muS[a * 2], sg = muS[a * 2 + 1];
                int swz = ((a15 ^ kposN) << 4) + ebyt;
                float sn = bf2f(*(const unsigned short*)((const char*)LNf + ((g * 8 + fragN) << 10) + swz));
                float sraw = (sn - bc) * rgc * sg + mu;
                float a_ss = acc3[0][g][j] + bss;
                float a_sv = acc3[1][g][j] + bsv;
                float a_vv = acc3[2][g][j] + bvv;
                size_t grow = (size_t)(atom0 + a);
                s_out[grow * H + c] = sraw + a_ss + a_sv * dotv[g][j];
#pragma unroll
                for (int d = 0; d < 3; d++) {
                    float vraw = bf2f(*(const unsigned short*)((const char*)VF[pb] + ((g * 24 + d * 8 + fragN) << 10) + swz));
                    v_out[(grow * 3 + d) * (size_t)H + c] = vraw + a_vv * accU[d][g][j];
                }
            }

        BAR();  // B4: epilogue LDS reads done before LNf/muS overwritten

        do_ln();       // LayerNorm for next tile -> LNf, muS
        pb ^= 1;
    }
}

extern "C" void kernel_launch(void* const* d_in, const int* in_sizes, int n_in,
                              void* d_out, int out_size, void* d_ws, size_t ws_size,
                              hipStream_t stream) {
    const float* s     = (const float*)d_in[0];
    const float* v     = (const float*)d_in[1];
    const float* gamma = (const float*)d_in[2];
    const float* beta  = (const float*)d_in[3];
    const float* U_W   = (const float*)d_in[4];
    const float* V_W   = (const float*)d_in[5];
    const float* W1    = (const float*)d_in[6];
    const float* b1    = (const float*)d_in[7];
    const float* W2    = (const float*)d_in[8];
    const float* b2    = (const float*)d_in[9];
    float* s_out = (float*)d_out;
    float* v_out = s_out + (size_t)NATOMS * H;
    unsigned short* P = (unsigned short*)d_ws;   // needs 917504 B

    pack_weights<<<dim3(224), dim3(256), 0, stream>>>(U_W, V_W, W1, W2, P);
    painn_main<<<dim3(PGRID), dim3(1024), 0, stream>>>(s, v, gamma, beta, b1, b2, P, s_out, v_out);
}

// Round 6
// 536.864 us; speedup vs baseline: 1.1808x; 1.1808x over previous
//
#include <hip/hip_runtime.h>
#include <stdint.h>

#define H 256
#define NATOMS 100000
#define MB 16
#define NBLK (NATOMS / MB)   // 6250

typedef float floatx4 __attribute__((ext_vector_type(4)));
typedef short short8 __attribute__((ext_vector_type(8)));
typedef short short4v __attribute__((ext_vector_type(4)));

__device__ __forceinline__ unsigned short f2bf(float x) {
    union { float f; uint32_t u; } c; c.f = x;
    return (unsigned short)((c.u + 0x7FFFu + ((c.u >> 16) & 1u)) >> 16);
}
__device__ __forceinline__ float bf2f(unsigned short h) {
    union { uint32_t u; float f; } c; c.u = ((uint32_t)h) << 16; return c.f;
}

// ---------------------------------------------------------------------------
// Pack weights (f32 [K][N] row-major) into bf16 MFMA-B-fragment order.
// frag fl = nb*(K/32)+kb; lane l holds W[kb*32+(l>>4)*8+e][nb*16+(l&15)].
// ws layout (bf16 elems): U@0, V@65536, W1@131072, W2@262144 (896KB total).
// ---------------------------------------------------------------------------
__global__ void pack_weights(const float* __restrict__ U_W, const float* __restrict__ V_W,
                             const float* __restrict__ W1, const float* __restrict__ W2,
                             unsigned short* __restrict__ P) {
    int gtid = blockIdx.x * 256 + threadIdx.x;
    int fid = gtid >> 6, l = gtid & 63;
    const float* src; int K, N, fl; unsigned short* dst;
    if (fid < 128)      { src = U_W; K = 256; N = 256; fl = fid;       dst = P; }
    else if (fid < 256) { src = V_W; K = 256; N = 256; fl = fid - 128; dst = P + 65536; }
    else if (fid < 512) { src = W1;  K = 512; N = 256; fl = fid - 256; dst = P + 131072; }
    else                { src = W2;  K = 256; N = 768; fl = fid - 512; dst = P + 262144; }
    int kbc = K >> 5;
    int nb = fl / kbc, kb = fl - nb * kbc;
    int k0 = kb * 32 + ((l >> 4) << 3);
    int n0 = nb * 16 + (l & 15);
    short8 outv;
#pragma unroll
    for (int e = 0; e < 8; e++) outv[e] = (short)f2bf(src[(size_t)(k0 + e) * N + n0]);
    *(short8*)(dst + (size_t)fl * 512 + l * 8) = outv;
}

// ---------------------------------------------------------------------------
// Fused PaiNN mixing: one block = 16 atoms, 512 threads (8 waves), short-lived,
// 2 blocks/CU (launch_bounds(512,4), LDS 40KB). Raw v held in regs (bf16,
// staging map), raw s in regs (f32, LN map); GEMM results hand off via LDS
// overlays -> zero global re-reads. v_out/s_out written full-line coalesced.
// LDS A-frags are 1KB, lane l reads 16B at frag*1024 + loff,
//   loff = (l>>4)*256 + ((l15^(l>>4))<<4)  (kpos-XOR swizzle).
// VF: v A-frags [d*8+ks] (24KB) -> Uv[16][3][256] bf16 (row-major, a-XOR).
// LNf: s_normed A-frags (8KB)   -> sdelta[16][256] bf16.
// NMf: Vv_norm A-frags -> hid A-frags -> a_vv[16][256] bf16.
// Wave w owns cols [32w,32w+32): c = 32w + 16cf + l15, cf in {0,1}.
// ---------------------------------------------------------------------------
__global__ __launch_bounds__(512, 4) void painn_main(
    const float* __restrict__ s, const float* __restrict__ v,
    const float* __restrict__ gamma, const float* __restrict__ beta,
    const float* __restrict__ b1, const float* __restrict__ b2,
    const unsigned short* __restrict__ P,
    float* __restrict__ s_out, float* __restrict__ v_out) {

    __shared__ unsigned short VF[12288];   // 24KB
    __shared__ unsigned short LNf[4096];   // 8KB
    __shared__ unsigned short NMf[4096];   // 8KB

    const int tid = threadIdx.x;
    const int w = tid >> 6, l = tid & 63;
    const int l15 = l & 15, lhi = l >> 4;
    const int loff = (lhi << 8) | ((l15 ^ lhi) << 4);
    const int atom0 = blockIdx.x * MB;
    const int aLN = tid >> 5, lg = tid & 31;
    const int nb0 = w << 1;

    // ---- stage v -> VF (A-frags), keep raw bf16 in regs ----
    short8 vstg[3];
    {
        const floatx4* vsrc = (const floatx4*)(v + (size_t)atom0 * 3 * H);
#pragma unroll
        for (int i = 0; i < 3; i++) {
            int p = i * 512 + tid;
            int a = p / 96; int rem = p - a * 96; int d = rem >> 5; int c8 = rem & 31;
            int q = ((a * 3 + d) << 6) + (c8 << 1);
            floatx4 x0 = vsrc[q], x1 = vsrc[q + 1];
            short8 pk;
#pragma unroll
            for (int j = 0; j < 4; j++) { pk[j] = (short)f2bf(x0[j]); pk[4 + j] = (short)f2bf(x1[j]); }
            vstg[i] = pk;
            int ks = c8 >> 2, kpos = c8 & 3;
            int bo = ((d * 8 + ks) << 10) + (kpos << 8) + ((a ^ kpos) << 4);
            *(short8*)((char*)VF + bo) = pk;
        }
    }

    // ---- LayerNorm(s) -> LNf (A-frags), keep raw f32 in regs ----
    floatx4 sr0, sr1;
    {
        const floatx4* srow = (const floatx4*)(s + (size_t)(atom0 + aLN) * H);
        sr0 = srow[lg]; sr1 = srow[lg + 32];
        float sum = 0.f, sq = 0.f;
#pragma unroll
        for (int j = 0; j < 4; j++) { sum += sr0[j] + sr1[j]; sq += sr0[j] * sr0[j] + sr1[j] * sr1[j]; }
#pragma unroll
        for (int m = 1; m < 32; m <<= 1) { sum += __shfl_xor(sum, m); sq += __shfl_xor(sq, m); }
        float mu = sum * (1.f / 256.f);
        float var = sq * (1.f / 256.f) - mu * mu;
        float rs = rsqrtf(var + 1e-5f);
#pragma unroll
        for (int i = 0; i < 2; i++) {
            int chunk = lg + (i << 5);
            floatx4 va = i ? sr1 : sr0;
            floatx4 g4 = *(const floatx4*)(gamma + chunk * 4);
            floatx4 be4 = *(const floatx4*)(beta + chunk * 4);
            short4v pk;
#pragma unroll
            for (int j = 0; j < 4; j++) pk[j] = (short)f2bf((va[j] - mu) * rs * g4[j] + be4[j]);
            int ks2 = chunk >> 3, kpos = (chunk >> 1) & 3, half = chunk & 1;
            int bo = (ks2 << 10) + (kpos << 8) + ((aLN ^ kpos) << 4) + half * 8;
            *(short4v*)((char*)LNf + bo) = pk;
        }
    }

    __syncthreads();   // B1: VF + LNf visible

    // ---- phase 1: Uv & Vv (M = 48 rows = (d,a), N = 256) ----
    floatx4 accU[3][2], accV[3][2];
#pragma unroll
    for (int d = 0; d < 3; d++)
#pragma unroll
        for (int cf = 0; cf < 2; cf++) { accU[d][cf] = (floatx4)0.f; accV[d][cf] = (floatx4)0.f; }
    {
        const short8* PU = (const short8*)P;
        const short8* PV = (const short8*)(P + 65536);
        short8 bU[2][2], bV[2][2];
#pragma unroll
        for (int cf = 0; cf < 2; cf++) {
            bU[0][cf] = PU[(size_t)((nb0 + cf) * 8) * 64 + l];
            bV[0][cf] = PV[(size_t)((nb0 + cf) * 8) * 64 + l];
        }
#pragma unroll
        for (int ks = 0; ks < 8; ks++) {
            int cur = ks & 1, nxt = cur ^ 1;
            if (ks < 7) {
#pragma unroll
                for (int cf = 0; cf < 2; cf++) {
                    bU[nxt][cf] = PU[(size_t)((nb0 + cf) * 8 + ks + 1) * 64 + l];
                    bV[nxt][cf] = PV[(size_t)((nb0 + cf) * 8 + ks + 1) * 64 + l];
                }
            }
            short8 afr[3];
#pragma unroll
            for (int d = 0; d < 3; d++)
                afr[d] = *(const short8*)((const char*)VF + ((d * 8 + ks) << 10) + loff);
            __builtin_amdgcn_s_setprio(1);
#pragma unroll
            for (int d = 0; d < 3; d++)
#pragma unroll
                for (int cf = 0; cf < 2; cf++) {
                    accU[d][cf] = __builtin_amdgcn_mfma_f32_16x16x32_bf16(afr[d], bU[cur][cf], accU[d][cf], 0, 0, 0);
                    accV[d][cf] = __builtin_amdgcn_mfma_f32_16x16x32_bf16(afr[d], bV[cur][cf], accV[d][cf], 0, 0, 0);
                }
            __builtin_amdgcn_s_setprio(0);
        }
    }

    // ---- dot_uv (regs) + ||Vv|| -> NMf (A-frag layout, k' = c) ----
    float dotv[2][4];
#pragma unroll
    for (int cf = 0; cf < 2; cf++)
#pragma unroll
        for (int j = 0; j < 4; j++) {
            float du = accU[0][cf][j] * accV[0][cf][j] + accU[1][cf][j] * accV[1][cf][j]
                     + accU[2][cf][j] * accV[2][cf][j];
            dotv[cf][j] = du;
            float nv = sqrtf(accV[0][cf][j] * accV[0][cf][j] + accV[1][cf][j] * accV[1][cf][j]
                           + accV[2][cf][j] * accV[2][cf][j] + 1e-8f);
            int a = (lhi << 2) + j;
            int c = (w << 5) + (cf << 4) + l15;
            int kpos = (c >> 3) & 3;
            int bo = (w << 10) + (kpos << 8) + ((a ^ kpos) << 4) + ((c & 7) << 1);
            *(unsigned short*)((char*)NMf + bo) = f2bf(nv);
        }

    __syncthreads();   // B1.5: p1 VF reads done; NMf norm visible

    // ---- Uv -> VF overlay (row-major [a][d][256] bf16, a-XOR swizzle) ----
#pragma unroll
    for (int cf = 0; cf < 2; cf++)
#pragma unroll
        for (int j = 0; j < 4; j++) {
            int a = (lhi << 2) + j;
            int c = (w << 5) + (cf << 4) + l15;
            int xo = (a & 7) << 4;
#pragma unroll
            for (int d = 0; d < 3; d++) {
                int bo = (((a * 3 + d) << 9) + (c << 1)) ^ xo;
                *(unsigned short*)((char*)VF + bo) = f2bf(accU[d][cf][j]);
            }
        }

    // ---- phase 2: hid = silu(ctx_in @ W1 + b1), M=16, K=512 ----
    floatx4 acc2[2];
    acc2[0] = (floatx4)0.f; acc2[1] = (floatx4)0.f;
    {
        const short8* PW1 = (const short8*)(P + 131072);
        short8 bw[2][2];
#pragma unroll
        for (int cf = 0; cf < 2; cf++)
            bw[0][cf] = PW1[(size_t)((nb0 + cf) * 16) * 64 + l];
#pragma unroll
        for (int ks2 = 0; ks2 < 16; ks2++) {
            int cur = ks2 & 1, nxt = cur ^ 1;
            if (ks2 < 15) {
#pragma unroll
                for (int cf = 0; cf < 2; cf++)
                    bw[nxt][cf] = PW1[(size_t)((nb0 + cf) * 16 + ks2 + 1) * 64 + l];
            }
            short8 af = (ks2 < 8)
                ? *(const short8*)((const char*)LNf + (ks2 << 10) + loff)
                : *(const short8*)((const char*)NMf + ((ks2 - 8) << 10) + loff);
            __builtin_amdgcn_s_setprio(1);
#pragma unroll
            for (int cf = 0; cf < 2; cf++)
                acc2[cf] = __builtin_amdgcn_mfma_f32_16x16x32_bf16(af, bw[cur][cf], acc2[cf], 0, 0, 0);
            __builtin_amdgcn_s_setprio(0);
        }
    }

    __syncthreads();   // B2.5: p2 LDS reads done -> NMf reusable as hid

    {
        float b1c0 = b1[(w << 5) + l15], b1c1 = b1[(w << 5) + 16 + l15];
#pragma unroll
        for (int cf = 0; cf < 2; cf++) {
            float bb = cf ? b1c1 : b1c0;
#pragma unroll
            for (int j = 0; j < 4; j++) {
                int a = (lhi << 2) + j;
                int c = (w << 5) + (cf << 4) + l15;
                float x = acc2[cf][j] + bb;
                float hh = x / (1.f + __expf(-x));
                int kpos = (c >> 3) & 3;
                int bo = (w << 10) + (kpos << 8) + ((a ^ kpos) << 4) + ((c & 7) << 1);
                *(unsigned short*)((char*)NMf + bo) = f2bf(hh);
            }
        }
    }

    __syncthreads();   // B3: hid visible

    // ---- phase 3: ctx = hid @ W2 + b2 (segments ss, sv, vv; matched strips) ----
    floatx4 acc3[3][2];
#pragma unroll
    for (int sg = 0; sg < 3; sg++)
#pragma unroll
        for (int cf = 0; cf < 2; cf++) acc3[sg][cf] = (floatx4)0.f;
    {
        const short8* PW2 = (const short8*)(P + 262144);
#pragma unroll
        for (int cf = 0; cf < 2; cf++) {
            short8 bw[2][3];
#pragma unroll
            for (int sg = 0; sg < 3; sg++)
                bw[0][sg] = PW2[(size_t)((sg * 16 + nb0 + cf) * 8) * 64 + l];
#pragma unroll
            for (int ks3 = 0; ks3 < 8; ks3++) {
                int cur = ks3 & 1, nxt = cur ^ 1;
                if (ks3 < 7) {
#pragma unroll
                    for (int sg = 0; sg < 3; sg++)
                        bw[nxt][sg] = PW2[(size_t)((sg * 16 + nb0 + cf) * 8 + ks3 + 1) * 64 + l];
                }
                short8 af = *(const short8*)((const char*)NMf + (ks3 << 10) + loff);
                __builtin_amdgcn_s_setprio(1);
#pragma unroll
                for (int sg = 0; sg < 3; sg++)
                    acc3[sg][cf] = __builtin_amdgcn_mfma_f32_16x16x32_bf16(af, bw[cur][sg], acc3[sg][cf], 0, 0, 0);
                __builtin_amdgcn_s_setprio(0);
            }
        }
    }

    __syncthreads();   // B3.5: p3 NMf reads done

    // ---- sdelta -> LNf overlay; a_vv -> NMf overlay ----
    {
        int cbase = (w << 5) + l15;
        float bss0 = b2[cbase], bss1 = b2[cbase + 16];
        float bsv0 = b2[256 + cbase], bsv1 = b2[256 + cbase + 16];
        float bvv0 = b2[512 + cbase], bvv1 = b2[512 + cbase + 16];
#pragma unroll
        for (int cf = 0; cf < 2; cf++) {
            float bssx = cf ? bss1 : bss0, bsvx = cf ? bsv1 : bsv0, bvvx = cf ? bvv1 : bvv0;
#pragma unroll
            for (int j = 0; j < 4; j++) {
                int a = (lhi << 2) + j;
                int c = cbase + (cf << 4);
                int xo = (a & 7) << 4;
                float sd = (acc3[0][cf][j] + bssx) + (acc3[1][cf][j] + bsvx) * dotv[cf][j];
                float av = acc3[2][cf][j] + bvvx;
                int bo = ((a << 9) + (c << 1)) ^ xo;
                *(unsigned short*)((char*)LNf + bo) = f2bf(sd);
                *(unsigned short*)((char*)NMf + bo) = f2bf(av);
            }
        }
    }

    __syncthreads();   // B4: handoffs visible

    // ---- epilogue: s_out (LN map, raw s from regs), full-line coalesced ----
    {
        size_t gbase = (size_t)(atom0 + aLN) * H;
        int xo = (aLN & 7) << 4;
#pragma unroll
        for (int i = 0; i < 2; i++) {
            int chunk = lg + (i << 5);
            short4v sd4 = *(const short4v*)((const char*)LNf + (((aLN << 9) + (chunk << 3)) ^ xo));
            floatx4 va = i ? sr1 : sr0;
            floatx4 o;
#pragma unroll
            for (int j = 0; j < 4; j++) o[j] = va[j] + bf2f(sd4[j]);
            *(floatx4*)(s_out + gbase + chunk * 4) = o;
        }
    }

    // ---- epilogue: v_out (staging map, raw v from regs), full-line coalesced ----
#pragma unroll
    for (int i = 0; i < 3; i++) {
        int p = i * 512 + tid;
        int a = p / 96; int rem = p - a * 96; int d = rem >> 5; int c8 = rem & 31;
        int xo = (a & 7) << 4;
        short8 uv8 = *(const short8*)((const char*)VF + ((((a * 3 + d) << 9) + (c8 << 4)) ^ xo));
        short8 av8 = *(const short8*)((const char*)NMf + (((a << 9) + (c8 << 4)) ^ xo));
        floatx4 o0, o1;
#pragma unroll
        for (int j = 0; j < 4; j++) {
            o0[j] = bf2f(vstg[i][j])     + bf2f(av8[j])     * bf2f(uv8[j]);
            o1[j] = bf2f(vstg[i][4 + j]) + bf2f(av8[4 + j]) * bf2f(uv8[4 + j]);
        }
        size_t vb = ((size_t)(atom0 + a) * 3 + d) * H + (c8 << 3);
        *(floatx4*)(v_out + vb) = o0;
        *(floatx4*)(v_out + vb + 4) = o1;
    }
}

extern "C" void kernel_launch(void* const* d_in, const int* in_sizes, int n_in,
                              void* d_out, int out_size, void* d_ws, size_t ws_size,
                              hipStream_t stream) {
    const float* s     = (const float*)d_in[0];
    const float* v     = (const float*)d_in[1];
    const float* gamma = (const float*)d_in[2];
    const float* beta  = (const float*)d_in[3];
    const float* U_W   = (const float*)d_in[4];
    const float* V_W   = (const float*)d_in[5];
    const float* W1    = (const float*)d_in[6];
    const float* b1    = (const float*)d_in[7];
    const float* W2    = (const float*)d_in[8];
    const float* b2    = (const float*)d_in[9];
    float* s_out = (float*)d_out;
    float* v_out = s_out + (size_t)NATOMS * H;
    unsigned short* P = (unsigned short*)d_ws;   // needs 917504 B

    pack_weights<<<dim3(224), dim3(256), 0, stream>>>(U_W, V_W, W1, W2, P);
    painn_main<<<dim3(NBLK), dim3(512), 0, stream>>>(s, v, gamma, beta, b1, b2, P, s_out, v_out);
}

// Round 7
// 473.425 us; speedup vs baseline: 1.3390x; 1.1340x over previous
//
#include <hip/hip_runtime.h>
#include <stdint.h>

#define H 256
#define NATOMS 100000
#define MB 32
#define NBLK (NATOMS / MB)   // 3125

typedef float floatx4 __attribute__((ext_vector_type(4)));
typedef short short8 __attribute__((ext_vector_type(8)));
typedef short short4v __attribute__((ext_vector_type(4)));

// lgkm-only barrier: vmcnt (global prefetches) stays in flight across it.
#define BAR() do { asm volatile("s_waitcnt lgkmcnt(0)\n\ts_barrier" ::: "memory"); __builtin_amdgcn_sched_barrier(0); } while (0)

__device__ __forceinline__ unsigned short f2bf(float x) {
    union { float f; uint32_t u; } c; c.f = x;
    return (unsigned short)((c.u + 0x7FFFu + ((c.u >> 16) & 1u)) >> 16);
}
__device__ __forceinline__ float bf2f(unsigned short h) {
    union { uint32_t u; float f; } c; c.u = ((uint32_t)h) << 16; return c.f;
}

// ---------------------------------------------------------------------------
// Pack weights (f32 [K][N] row-major) into bf16 MFMA-B-fragment order.
// frag fl = nb*(K/32)+kb; lane l holds W[kb*32+(l>>4)*8+e][nb*16+(l&15)].
// ws layout (bf16 elems): U@0, V@65536, W1@131072, W2@262144 (896KB total).
// ---------------------------------------------------------------------------
__global__ void pack_weights(const float* __restrict__ U_W, const float* __restrict__ V_W,
                             const float* __restrict__ W1, const float* __restrict__ W2,
                             unsigned short* __restrict__ P) {
    int gtid = blockIdx.x * 256 + threadIdx.x;
    int fid = gtid >> 6, l = gtid & 63;
    const float* src; int K, N, fl; unsigned short* dst;
    if (fid < 128)      { src = U_W; K = 256; N = 256; fl = fid;       dst = P; }
    else if (fid < 256) { src = V_W; K = 256; N = 256; fl = fid - 128; dst = P + 65536; }
    else if (fid < 512) { src = W1;  K = 512; N = 256; fl = fid - 256; dst = P + 131072; }
    else                { src = W2;  K = 256; N = 768; fl = fid - 512; dst = P + 262144; }
    int kbc = K >> 5;
    int nb = fl / kbc, kb = fl - nb * kbc;
    int k0 = kb * 32 + ((l >> 4) << 3);
    int n0 = nb * 16 + (l & 15);
    short8 outv;
#pragma unroll
    for (int e = 0; e < 8; e++) outv[e] = (short)f2bf(src[(size_t)(k0 + e) * N + n0]);
    *(short8*)(dst + (size_t)fl * 512 + l * 8) = outv;
}

// ---------------------------------------------------------------------------
// Fused PaiNN mixing. Block = 32 atoms, 1024 thr (16 waves), 128KB LDS,
// 1 block/CU. Wave w owns cols [16w,16w+16). A-frags are 1KB MFMA-linear:
// element (a15, koff): kpos=(koff>>3)&3, byte = kpos*256+((a15^kpos)<<4)+(koff&7)*2;
// lane read offset loff = (l>>4)*256 + ((l15^(l>>4))<<4).
// VF : raw v frags [g*24+d*8+ks] (48KB, live to epilogue)
// UVf: Uv row-major [a][d][c] bf16, a-XOR (48KB, after p1)
// LNf: s_norm frags [g*8+ks] (16KB) -> sdelta [a][c] (after p3)
// NMf: Vv_norm frags -> hid frags -> a_vv [a][c] (16KB)
// B-streams: depth-4 (p1,p2) / depth-3 (p3) register slot pipelines, first
// slots issued BEFORE the preceding lgkm-only barrier (loads stay in flight).
// ---------------------------------------------------------------------------
__global__ __launch_bounds__(1024, 4) void painn_main(
    const float* __restrict__ s, const float* __restrict__ v,
    const float* __restrict__ gamma, const float* __restrict__ beta,
    const float* __restrict__ b1, const float* __restrict__ b2,
    const unsigned short* __restrict__ P,
    float* __restrict__ s_out, float* __restrict__ v_out) {

    __shared__ unsigned short VF[24576];   // 48KB
    __shared__ unsigned short UVf[24576];  // 48KB
    __shared__ unsigned short LNf[8192];   // 16KB
    __shared__ unsigned short NMf[8192];   // 16KB

    const int tid = threadIdx.x;
    const int w = tid >> 6, l = tid & 63;
    const int l15 = l & 15, lhi = l >> 4;
    const int loff = (lhi << 8) | ((l15 ^ lhi) << 4);
    const int atom0 = blockIdx.x * MB;
    const int aLN = tid >> 5, lg = tid & 31;
    const int c = (w << 4) | l15;
    const int kposN = ((w << 1) | (l15 >> 3)) & 3;
    const int fragN = w >> 1;                       // c>>5
    const int ebyt = (kposN << 8) | ((c & 7) << 1);

    // ---- stage v -> VF (raw bf16 A-frags; survives to epilogue) ----
    {
        const floatx4* vsrc = (const floatx4*)(v + (size_t)atom0 * 3 * H);
#pragma unroll
        for (int i = 0; i < 3; i++) {
            int p = i * 1024 + tid;
            int a = p / 96; int rem = p - a * 96; int d = rem >> 5; int c8 = rem & 31;
            int q = ((a * 3 + d) << 6) + (c8 << 1);
            floatx4 x0 = vsrc[q], x1 = vsrc[q + 1];
            short8 pk;
#pragma unroll
            for (int j = 0; j < 4; j++) { pk[j] = (short)f2bf(x0[j]); pk[4 + j] = (short)f2bf(x1[j]); }
            int ks = c8 >> 2, kpos = c8 & 3;
            int g = a >> 4, a15 = a & 15;
            int bo = ((g * 24 + d * 8 + ks) << 10) + (kpos << 8) + ((a15 ^ kpos) << 4);
            *(short8*)((char*)VF + bo) = pk;
        }
    }

    // ---- LayerNorm(s) -> LNf frags; raw s kept in regs (f32) ----
    floatx4 sr0, sr1;
    {
        const floatx4* srow = (const floatx4*)(s + (size_t)(atom0 + aLN) * H);
        sr0 = srow[lg]; sr1 = srow[lg + 32];
        float sum = 0.f, sq = 0.f;
#pragma unroll
        for (int j = 0; j < 4; j++) { sum += sr0[j] + sr1[j]; sq += sr0[j] * sr0[j] + sr1[j] * sr1[j]; }
#pragma unroll
        for (int m = 1; m < 32; m <<= 1) { sum += __shfl_xor(sum, m); sq += __shfl_xor(sq, m); }
        float mu = sum * (1.f / 256.f);
        float var = sq * (1.f / 256.f) - mu * mu;
        float rs = rsqrtf(var + 1e-5f);
        int g = aLN >> 4, a15 = aLN & 15;
#pragma unroll
        for (int i = 0; i < 2; i++) {
            int chunk = lg + (i << 5);
            floatx4 va = i ? sr1 : sr0;
            floatx4 g4 = *(const floatx4*)(gamma + chunk * 4);
            floatx4 be4 = *(const floatx4*)(beta + chunk * 4);
            short4v pk;
#pragma unroll
            for (int j = 0; j < 4; j++) pk[j] = (short)f2bf((va[j] - mu) * rs * g4[j] + be4[j]);
            int ks2 = chunk >> 3, kpos = (chunk >> 1) & 3, half = chunk & 1;
            int bo = ((g * 8 + ks2) << 10) + (kpos << 8) + ((a15 ^ kpos) << 4) + half * 8;
            *(short4v*)((char*)LNf + bo) = pk;
        }
    }

    // ---- p1 B prefetch (slots 0..2) BEFORE barrier: hides under staging ----
    const short8* PU = (const short8*)P;
    const short8* PV = (const short8*)(P + 65536);
    short8 bU[4], bV[4];
#pragma unroll
    for (int pre = 0; pre < 3; pre++) {
        bU[pre] = PU[(size_t)(w * 8 + pre) * 64 + l];
        bV[pre] = PV[(size_t)(w * 8 + pre) * 64 + l];
    }

    BAR();  // B1: VF + LNf visible (vmcnt NOT drained)

    // ---- phase 1: Uv & Vv (M=96: 3d x 2g x 16a; N strip = 16 cols/wave) ----
    floatx4 accU[3][2], accV[3][2];
#pragma unroll
    for (int d = 0; d < 3; d++)
#pragma unroll
        for (int g = 0; g < 2; g++) { accU[d][g] = (floatx4)0.f; accV[d][g] = (floatx4)0.f; }
#pragma unroll
    for (int ks = 0; ks < 8; ks++) {
        if (ks < 5) {
            bU[(ks + 3) & 3] = PU[(size_t)(w * 8 + ks + 3) * 64 + l];
            bV[(ks + 3) & 3] = PV[(size_t)(w * 8 + ks + 3) * 64 + l];
        }
        short8 afr[3][2];
#pragma unroll
        for (int d = 0; d < 3; d++)
#pragma unroll
            for (int g = 0; g < 2; g++)
                afr[d][g] = *(const short8*)((const char*)VF + ((g * 24 + d * 8 + ks) << 10) + loff);
        __builtin_amdgcn_s_setprio(1);
#pragma unroll
        for (int d = 0; d < 3; d++)
#pragma unroll
            for (int g = 0; g < 2; g++) {
                accU[d][g] = __builtin_amdgcn_mfma_f32_16x16x32_bf16(afr[d][g], bU[ks & 3], accU[d][g], 0, 0, 0);
                accV[d][g] = __builtin_amdgcn_mfma_f32_16x16x32_bf16(afr[d][g], bV[ks & 3], accV[d][g], 0, 0, 0);
            }
        __builtin_amdgcn_s_setprio(0);
    }

    // ---- dot_uv (regs), ||Vv|| -> NMf frags, Uv -> UVf ----
    float dotv[2][4];
#pragma unroll
    for (int g = 0; g < 2; g++)
#pragma unroll
        for (int j = 0; j < 4; j++) {
            float du = accU[0][g][j] * accV[0][g][j] + accU[1][g][j] * accV[1][g][j]
                     + accU[2][g][j] * accV[2][g][j];
            dotv[g][j] = du;
            float nv = sqrtf(accV[0][g][j] * accV[0][g][j] + accV[1][g][j] * accV[1][g][j]
                           + accV[2][g][j] * accV[2][g][j] + 1e-8f);
            int a15 = (lhi << 2) + j;
            int bo = ((g * 8 + fragN) << 10) + ((a15 ^ kposN) << 4) + ebyt;
            *(unsigned short*)((char*)NMf + bo) = f2bf(nv);
            int a = (g << 4) + a15;
            int xo = (a & 7) << 4;
#pragma unroll
            for (int d = 0; d < 3; d++) {
                int bo2 = ((((a * 3 + d) << 9) + (c << 1))) ^ xo;
                *(unsigned short*)((char*)UVf + bo2) = f2bf(accU[d][g][j]);
            }
        }

    // ---- p2 B prefetch before barrier ----
    const short8* PW1 = (const short8*)(P + 131072);
    short8 bw1[4];
#pragma unroll
    for (int pre = 0; pre < 3; pre++) bw1[pre] = PW1[(size_t)(w * 16 + pre) * 64 + l];

    BAR();  // B1.5: norm + Uv visible; p1 VF reads done

    // ---- phase 2: hid = silu(ctx_in @ W1 + b1), M=32, K=512 ----
    floatx4 acc2[2];
    acc2[0] = (floatx4)0.f; acc2[1] = (floatx4)0.f;
#pragma unroll
    for (int ks2 = 0; ks2 < 16; ks2++) {
        if (ks2 < 13) bw1[(ks2 + 3) & 3] = PW1[(size_t)(w * 16 + ks2 + 3) * 64 + l];
        short8 af[2];
#pragma unroll
        for (int g = 0; g < 2; g++)
            af[g] = (ks2 < 8)
                ? *(const short8*)((const char*)LNf + ((g * 8 + ks2) << 10) + loff)
                : *(const short8*)((const char*)NMf + ((g * 8 + ks2 - 8) << 10) + loff);
        __builtin_amdgcn_s_setprio(1);
#pragma unroll
        for (int g = 0; g < 2; g++)
            acc2[g] = __builtin_amdgcn_mfma_f32_16x16x32_bf16(af[g], bw1[ks2 & 3], acc2[g], 0, 0, 0);
        __builtin_amdgcn_s_setprio(0);
    }

    BAR();  // B2.5: p2 NMf reads done -> NMf reusable as hid

    // ---- hid -> NMf frags ----
    {
        float bb = b1[c];
#pragma unroll
        for (int g = 0; g < 2; g++)
#pragma unroll
            for (int j = 0; j < 4; j++) {
                int a15 = (lhi << 2) + j;
                float x = acc2[g][j] + bb;
                float hh = x / (1.f + __expf(-x));
                int bo = ((g * 8 + fragN) << 10) + ((a15 ^ kposN) << 4) + ebyt;
                *(unsigned short*)((char*)NMf + bo) = f2bf(hh);
            }
    }

    // ---- p3 B prefetch (2 iters deep) before barrier ----
    const short8* PW2 = (const short8*)(P + 262144);
    short8 bw2[3][3];
#pragma unroll
    for (int pre = 0; pre < 2; pre++)
#pragma unroll
        for (int sg = 0; sg < 3; sg++)
            bw2[pre][sg] = PW2[(size_t)((sg * 16 + w) * 8 + pre) * 64 + l];

    BAR();  // B3: hid visible

    // ---- phase 3: ctx = hid @ W2 + b2 (ss, sv, vv; matched 16-col strips) ----
    floatx4 acc3[3][2];
#pragma unroll
    for (int sg = 0; sg < 3; sg++)
#pragma unroll
        for (int g = 0; g < 2; g++) acc3[sg][g] = (floatx4)0.f;
#pragma unroll
    for (int ks3 = 0; ks3 < 8; ks3++) {
        if (ks3 < 6) {
#pragma unroll
            for (int sg = 0; sg < 3; sg++)
                bw2[(ks3 + 2) % 3][sg] = PW2[(size_t)((sg * 16 + w) * 8 + ks3 + 2) * 64 + l];
        }
        short8 af[2];
#pragma unroll
        for (int g = 0; g < 2; g++)
            af[g] = *(const short8*)((const char*)NMf + ((g * 8 + ks3) << 10) + loff);
        __builtin_amdgcn_s_setprio(1);
#pragma unroll
        for (int sg = 0; sg < 3; sg++)
#pragma unroll
            for (int g = 0; g < 2; g++)
                acc3[sg][g] = __builtin_amdgcn_mfma_f32_16x16x32_bf16(af[g], bw2[ks3 % 3][sg], acc3[sg][g], 0, 0, 0);
        __builtin_amdgcn_s_setprio(0);
    }

    BAR();  // B3.5: p3 NMf reads done

    // ---- sdelta -> LNf [a][c]; a_vv -> NMf [a][c] ----
    {
        float bss = b2[c], bsv = b2[256 + c], bvv = b2[512 + c];
#pragma unroll
        for (int g = 0; g < 2; g++)
#pragma unroll
            for (int j = 0; j < 4; j++) {
                int a = (g << 4) + (lhi << 2) + j;
                int xo = (a & 7) << 4;
                float sd = (acc3[0][g][j] + bss) + (acc3[1][g][j] + bsv) * dotv[g][j];
                float av = acc3[2][g][j] + bvv;
                int bo = ((a << 9) + (c << 1)) ^ xo;
                *(unsigned short*)((char*)LNf + bo) = f2bf(sd);
                *(unsigned short*)((char*)NMf + bo) = f2bf(av);
            }
    }

    BAR();  // B4: handoffs visible

    // ---- epilogue: s_out (raw s from regs + sdelta), full-line coalesced ----
    {
        size_t gbase = (size_t)(atom0 + aLN) * H;
        int xo = (aLN & 7) << 4;
#pragma unroll
        for (int i = 0; i < 2; i++) {
            int chunk = lg + (i << 5);
            short4v sd4 = *(const short4v*)((const char*)LNf + (((aLN << 9) + (chunk << 3)) ^ xo));
            floatx4 va = i ? sr1 : sr0;
            floatx4 o;
#pragma unroll
            for (int j = 0; j < 4; j++) o[j] = va[j] + bf2f(sd4[j]);
            *(floatx4*)(s_out + gbase + chunk * 4) = o;
        }
    }

    // ---- epilogue: v_out = v + a_vv * Uv (all from LDS), full-line coalesced ----
#pragma unroll
    for (int i = 0; i < 3; i++) {
        int p = i * 1024 + tid;
        int a = p / 96; int rem = p - a * 96; int d = rem >> 5; int c8 = rem & 31;
        int g = a >> 4, a15 = a & 15;
        int ks = c8 >> 2, kpos = c8 & 3;
        int xo = (a & 7) << 4;
        short8 vr8 = *(const short8*)((const char*)VF + ((g * 24 + d * 8 + ks) << 10) + (kpos << 8) + ((a15 ^ kpos) << 4));
        short8 uv8 = *(const short8*)((const char*)UVf + ((((a * 3 + d) << 9) + (c8 << 4)) ^ xo));
        short8 av8 = *(const short8*)((const char*)NMf + (((a << 9) + (c8 << 4)) ^ xo));
        floatx4 o0, o1;
#pragma unroll
        for (int j = 0; j < 4; j++) {
            o0[j] = bf2f(vr8[j])     + bf2f(av8[j])     * bf2f(uv8[j]);
            o1[j] = bf2f(vr8[4 + j]) + bf2f(av8[4 + j]) * bf2f(uv8[4 + j]);
        }
        size_t vb = ((size_t)(atom0 + a) * 3 + d) * H + (c8 << 3);
        *(floatx4*)(v_out + vb) = o0;
        *(floatx4*)(v_out + vb + 4) = o1;
    }
}

extern "C" void kernel_launch(void* const* d_in, const int* in_sizes, int n_in,
                              void* d_out, int out_size, void* d_ws, size_t ws_size,
                              hipStream_t stream) {
    const float* s     = (const float*)d_in[0];
    const float* v     = (const float*)d_in[1];
    const float* gamma = (const float*)d_in[2];
    const float* beta  = (const float*)d_in[3];
    const float* U_W   = (const float*)d_in[4];
    const float* V_W   = (const float*)d_in[5];
    const float* W1    = (const float*)d_in[6];
    const float* b1    = (const float*)d_in[7];
    const float* W2    = (const float*)d_in[8];
    const float* b2    = (const float*)d_in[9];
    float* s_out = (float*)d_out;
    float* v_out = s_out + (size_t)NATOMS * H;
    unsigned short* P = (unsigned short*)d_ws;   // needs 917504 B

    pack_weights<<<dim3(224), dim3(256), 0, stream>>>(U_W, V_W, W1, W2, P);
    painn_main<<<dim3(NBLK), dim3(1024), 0, stream>>>(s, v, gamma, beta, b1, b2, P, s_out, v_out);
}

// Round 8
// 392.714 us; speedup vs baseline: 1.6142x; 1.2055x over previous
//
#include <hip/hip_runtime.h>
#include <stdint.h>

#define H 256
#define NATOMS 100000
#define MB 32
#define NBLK (NATOMS / MB)   // 3125

typedef float floatx4 __attribute__((ext_vector_type(4)));
typedef short short8 __attribute__((ext_vector_type(8)));
typedef short short4v __attribute__((ext_vector_type(4)));

// lgkm-only barrier: global prefetches stay in flight across it.
#define BAR() do { asm volatile("s_waitcnt lgkmcnt(0)\n\ts_barrier" ::: "memory"); __builtin_amdgcn_sched_barrier(0); } while (0)

__device__ __forceinline__ unsigned short f2bf(float x) {
    union { float f; uint32_t u; } c; c.f = x;
    return (unsigned short)((c.u + 0x7FFFu + ((c.u >> 16) & 1u)) >> 16);
}
__device__ __forceinline__ float bf2f(unsigned short h) {
    union { uint32_t u; float f; } c; c.u = ((uint32_t)h) << 16; return c.f;
}
__device__ __forceinline__ uint32_t pk2(float lo, float hi) {
    return (uint32_t)f2bf(lo) | ((uint32_t)f2bf(hi) << 16);
}
__device__ __forceinline__ float upk(uint32_t u, int hi) {
    union { uint32_t u; float f; } c;
    c.u = hi ? (u & 0xFFFF0000u) : (u << 16);
    return c.f;
}

// ---------------------------------------------------------------------------
// Pack weights (f32 [K][N] row-major) into bf16 MFMA-B-fragment order.
// frag fl = nb*(K/32)+kb; lane l holds W[kb*32+(l>>4)*8+e][nb*16+(l&15)].
// ws layout (bf16 elems): U@0, V@65536, W1@131072, W2@262144 (896KB total).
// ---------------------------------------------------------------------------
__global__ void pack_weights(const float* __restrict__ U_W, const float* __restrict__ V_W,
                             const float* __restrict__ W1, const float* __restrict__ W2,
                             unsigned short* __restrict__ P) {
    int gtid = blockIdx.x * 256 + threadIdx.x;
    int fid = gtid >> 6, l = gtid & 63;
    const float* src; int K, N, fl; unsigned short* dst;
    if (fid < 128)      { src = U_W; K = 256; N = 256; fl = fid;       dst = P; }
    else if (fid < 256) { src = V_W; K = 256; N = 256; fl = fid - 128; dst = P + 65536; }
    else if (fid < 512) { src = W1;  K = 512; N = 256; fl = fid - 256; dst = P + 131072; }
    else                { src = W2;  K = 256; N = 768; fl = fid - 512; dst = P + 262144; }
    int kbc = K >> 5;
    int nb = fl / kbc, kb = fl - nb * kbc;
    int k0 = kb * 32 + ((l >> 4) << 3);
    int n0 = nb * 16 + (l & 15);
    short8 outv;
#pragma unroll
    for (int e = 0; e < 8; e++) outv[e] = (short)f2bf(src[(size_t)(k0 + e) * N + n0]);
    *(short8*)(dst + (size_t)fl * 512 + l * 8) = outv;
}

// ---------------------------------------------------------------------------
// Fused PaiNN mixing. Block = 32 atoms, 512 thr (8 waves), LDS 64KB ->
// 2 blocks/CU (two independent barrier domains). Wave w owns cols
// [32w,32w+32) (cf 0..1). A-frags 1KB MFMA-linear w/ kpos-XOR swizzle;
// lane read off loff = (l>>4)*256 + ((l15^(l>>4))<<4).
// LDS map (one 64KB array):
//   [0,48K)  v-frags (g*24+d*8+ks)   [staging -> end of p1]
//   [0,16K)  slotX: Vv_norm frags (g*8+kn)  [B2 -> p2], then sdelta[a][c] [p3 -> epi]
//   [16K,32K) slotY: hid frags (g*8+ks)     [p2 -> p3]
//   [48K,64K) LNf: s_norm frags (g*8+ks)    [stage -> p2]
// In regs: raw s (bf16, srp), Uv (bf16 packed, uvh), dot_uv, a_vv.
// Per-cf p1 / per-seg p3 passes keep VGPR <= 128 (4 waves/SIMD).
// ---------------------------------------------------------------------------
__global__ __launch_bounds__(512, 4) void painn_main(
    const float* __restrict__ s, const float* __restrict__ v,
    const float* __restrict__ gamma, const float* __restrict__ beta,
    const float* __restrict__ b1, const float* __restrict__ b2,
    const unsigned short* __restrict__ P,
    float* __restrict__ s_out, float* __restrict__ v_out) {

    __shared__ unsigned short SH[32768];   // 64KB
    char* LB = (char*)SH;

    const int tid = threadIdx.x;
    const int w = tid >> 6, l = tid & 63;
    const int l15 = l & 15, lhi = l >> 4;
    const int loff = (lhi << 8) | ((l15 ^ lhi) << 4);
    const int atom0 = blockIdx.x * MB;
    const int aLN = tid >> 4, lg = tid & 15;          // 16 lanes per atom
    const int gLN = aLN >> 4, a15LN = aLN & 15;

    // ---- stage v -> v-frags [0,48K) ----
    {
        const floatx4* vsrc = (const floatx4*)(v + (size_t)atom0 * 3 * H);
#pragma unroll
        for (int i = 0; i < 6; i++) {
            int p = i * 512 + tid;
            int a = p / 96, rem = p - a * 96;
            int d = rem >> 5, c8 = rem & 31;
            int q = ((a * 3 + d) << 6) + (c8 << 1);
            floatx4 x0 = vsrc[q], x1 = vsrc[q + 1];
            short8 pk;
#pragma unroll
            for (int j = 0; j < 4; j++) { pk[j] = (short)f2bf(x0[j]); pk[4 + j] = (short)f2bf(x1[j]); }
            int ks = c8 >> 2, kpos = c8 & 3;
            int bo = ((((a >> 4) * 24) + d * 8 + ks) << 10) + (kpos << 8) + (((a & 15) ^ kpos) << 4);
            *(short8*)(LB + bo) = pk;
        }
    }

    // ---- LayerNorm(s) -> LNf frags [48K,64K); raw s packed in regs ----
    short4v srp[4];
    {
        const floatx4* srow = (const floatx4*)(s + (size_t)(atom0 + aLN) * H);
        floatx4 vals[4];
        float sum = 0.f, sq = 0.f;
#pragma unroll
        for (int i = 0; i < 4; i++) {
            vals[i] = srow[lg + (i << 4)];
#pragma unroll
            for (int j = 0; j < 4; j++) { sum += vals[i][j]; sq += vals[i][j] * vals[i][j]; }
        }
#pragma unroll
        for (int m = 1; m < 16; m <<= 1) { sum += __shfl_xor(sum, m); sq += __shfl_xor(sq, m); }
        float mu = sum * (1.f / 256.f);
        float var = sq * (1.f / 256.f) - mu * mu;
        float rs = rsqrtf(var + 1e-5f);
#pragma unroll
        for (int i = 0; i < 4; i++) {
            int chunk = lg + (i << 4);
            floatx4 g4 = *(const floatx4*)(gamma + chunk * 4);
            floatx4 be4 = *(const floatx4*)(beta + chunk * 4);
            short4v pk, pr;
#pragma unroll
            for (int j = 0; j < 4; j++) {
                pk[j] = (short)f2bf((vals[i][j] - mu) * rs * g4[j] + be4[j]);
                pr[j] = (short)f2bf(vals[i][j]);
            }
            srp[i] = pr;
            int ks2 = chunk >> 3, kpos = (chunk >> 1) & 3, half = chunk & 1;
            int bo = 49152 + ((gLN * 8 + ks2) << 10) + (kpos << 8) + ((a15LN ^ kpos) << 4) + half * 8;
            *(short4v*)(LB + bo) = pk;
        }
    }

    // ---- p1 B prefetch (cf=0, slot0) before barrier ----
    const short8* PU = (const short8*)P;
    const short8* PV = (const short8*)(P + 65536);
    short8 bU[2], bV[2];
    bU[0] = PU[(size_t)((w * 2) * 8) * 64 + l];
    bV[0] = PV[(size_t)((w * 2) * 8) * 64 + l];

    BAR();  // B1: v-frags + LNf visible

    // ---- phase 1: Uv & Vv, per-cf passes (keeps VGPR low) ----
    float dotv[2][2][4];
    uint32_t uvh[2][3][2][2];   // [cf][d][g][pair] packed bf16
    uint32_t nvp[2][2][2];      // [cf][g][pair]   packed bf16
#pragma unroll
    for (int cf = 0; cf < 2; cf++) {
        int nb = w * 2 + cf;
        if (cf == 1) {
            bU[0] = PU[(size_t)(nb * 8) * 64 + l];
            bV[0] = PV[(size_t)(nb * 8) * 64 + l];
        }
        floatx4 accU[3][2], accV[3][2];
#pragma unroll
        for (int d = 0; d < 3; d++)
#pragma unroll
            for (int g = 0; g < 2; g++) { accU[d][g] = (floatx4)0.f; accV[d][g] = (floatx4)0.f; }
#pragma unroll
        for (int ks = 0; ks < 8; ks++) {
            int cur = ks & 1, nxt = cur ^ 1;
            if (ks < 7) {
                bU[nxt] = PU[(size_t)(nb * 8 + ks + 1) * 64 + l];
                bV[nxt] = PV[(size_t)(nb * 8 + ks + 1) * 64 + l];
            }
#pragma unroll
            for (int g = 0; g < 2; g++) {
                short8 af0 = *(const short8*)(LB + ((g * 24 + 0 * 8 + ks) << 10) + loff);
                short8 af1 = *(const short8*)(LB + ((g * 24 + 1 * 8 + ks) << 10) + loff);
                short8 af2 = *(const short8*)(LB + ((g * 24 + 2 * 8 + ks) << 10) + loff);
                __builtin_amdgcn_s_setprio(1);
                accU[0][g] = __builtin_amdgcn_mfma_f32_16x16x32_bf16(af0, bU[cur], accU[0][g], 0, 0, 0);
                accV[0][g] = __builtin_amdgcn_mfma_f32_16x16x32_bf16(af0, bV[cur], accV[0][g], 0, 0, 0);
                accU[1][g] = __builtin_amdgcn_mfma_f32_16x16x32_bf16(af1, bU[cur], accU[1][g], 0, 0, 0);
                accV[1][g] = __builtin_amdgcn_mfma_f32_16x16x32_bf16(af1, bV[cur], accV[1][g], 0, 0, 0);
                accU[2][g] = __builtin_amdgcn_mfma_f32_16x16x32_bf16(af2, bU[cur], accU[2][g], 0, 0, 0);
                accV[2][g] = __builtin_amdgcn_mfma_f32_16x16x32_bf16(af2, bV[cur], accV[2][g], 0, 0, 0);
                __builtin_amdgcn_s_setprio(0);
            }
        }
        // fold: dot_uv, ||Vv||, pack Uv -> bf16
#pragma unroll
        for (int g = 0; g < 2; g++) {
            float nv[4];
#pragma unroll
            for (int j = 0; j < 4; j++) {
                dotv[cf][g][j] = accU[0][g][j] * accV[0][g][j] + accU[1][g][j] * accV[1][g][j]
                               + accU[2][g][j] * accV[2][g][j];
                nv[j] = sqrtf(accV[0][g][j] * accV[0][g][j] + accV[1][g][j] * accV[1][g][j]
                            + accV[2][g][j] * accV[2][g][j] + 1e-8f);
            }
            nvp[cf][g][0] = pk2(nv[0], nv[1]);
            nvp[cf][g][1] = pk2(nv[2], nv[3]);
#pragma unroll
            for (int d = 0; d < 3; d++) {
                uvh[cf][d][g][0] = pk2(accU[d][g][0], accU[d][g][1]);
                uvh[cf][d][g][1] = pk2(accU[d][g][2], accU[d][g][3]);
            }
        }
    }

    BAR();  // B2: all v-frag reads done -> slotX/slotY writable

    // ---- Vv_norm -> slotX frags ----
#pragma unroll
    for (int cf = 0; cf < 2; cf++) {
        int kp = (cf << 1) | (l15 >> 3);
        int cb = (l15 & 7) << 1;
#pragma unroll
        for (int g = 0; g < 2; g++)
#pragma unroll
            for (int j = 0; j < 4; j++) {
                int a15 = (lhi << 2) + j;
                unsigned short hbits = (unsigned short)((j & 1) ? (nvp[cf][g][j >> 1] >> 16)
                                                                : (nvp[cf][g][j >> 1] & 0xFFFF));
                int bo = ((g * 8 + w) << 10) + (kp << 8) + ((a15 ^ kp) << 4) + cb;
                *(unsigned short*)(LB + bo) = hbits;
            }
    }

    // ---- p2 B prefetch ----
    const short8* PW1 = (const short8*)(P + 131072);
    short8 bw[2];
    bw[0] = PW1[(size_t)((w * 2) * 16) * 64 + l];

    BAR();  // B3: norm frags visible

    // ---- phase 2: hid = silu(ctx_in @ W1 + b1), per-cf passes ----
#pragma unroll
    for (int cf = 0; cf < 2; cf++) {
        int nb = w * 2 + cf;
        if (cf == 1) bw[0] = PW1[(size_t)(nb * 16) * 64 + l];
        floatx4 acc2[2];
        acc2[0] = (floatx4)0.f; acc2[1] = (floatx4)0.f;
#pragma unroll
        for (int ks2 = 0; ks2 < 16; ks2++) {
            int cur = ks2 & 1, nxt = cur ^ 1;
            if (ks2 < 15) bw[nxt] = PW1[(size_t)(nb * 16 + ks2 + 1) * 64 + l];
            short8 af0 = (ks2 < 8)
                ? *(const short8*)(LB + 49152 + ((0 * 8 + ks2) << 10) + loff)
                : *(const short8*)(LB + ((0 * 8 + ks2 - 8) << 10) + loff);
            short8 af1 = (ks2 < 8)
                ? *(const short8*)(LB + 49152 + ((1 * 8 + ks2) << 10) + loff)
                : *(const short8*)(LB + ((1 * 8 + ks2 - 8) << 10) + loff);
            __builtin_amdgcn_s_setprio(1);
            acc2[0] = __builtin_amdgcn_mfma_f32_16x16x32_bf16(af0, bw[cur], acc2[0], 0, 0, 0);
            acc2[1] = __builtin_amdgcn_mfma_f32_16x16x32_bf16(af1, bw[cur], acc2[1], 0, 0, 0);
            __builtin_amdgcn_s_setprio(0);
        }
        // hid -> slotY frags (slotY free since B2; readers gated by B4)
        int c = (w << 5) + (cf << 4) + l15;
        float bb = b1[c];
        int kp = (cf << 1) | (l15 >> 3);
        int cb = (l15 & 7) << 1;
#pragma unroll
        for (int g = 0; g < 2; g++)
#pragma unroll
            for (int j = 0; j < 4; j++) {
                int a15 = (lhi << 2) + j;
                float x = acc2[g][j] + bb;
                float hh = x / (1.f + __expf(-x));
                int bo = 16384 + ((g * 8 + w) << 10) + (kp << 8) + ((a15 ^ kp) << 4) + cb;
                *(unsigned short*)(LB + bo) = f2bf(hh);
            }
    }

    // ---- p3 B prefetch (first pass = sv segment, sg=1) ----
    const short8* PW2 = (const short8*)(P + 262144);
    short8 b2w[2][2];
    b2w[0][0] = PW2[(size_t)((16 + w * 2 + 0) * 8) * 64 + l];
    b2w[0][1] = PW2[(size_t)((16 + w * 2 + 1) * 8) * 64 + l];

    BAR();  // B4: hid visible

    // ---- phase 3: per-segment passes sv -> ss -> vv ----
    float svd[2][2][4];   // sv*dot -> sdelta -> a_vv (reused)
    {   // sv (sg=1)
        floatx4 acc[2][2];
#pragma unroll
        for (int g = 0; g < 2; g++) { acc[g][0] = (floatx4)0.f; acc[g][1] = (floatx4)0.f; }
#pragma unroll
        for (int ks3 = 0; ks3 < 8; ks3++) {
            int cur = ks3 & 1, nxt = cur ^ 1;
            if (ks3 < 7) {
                b2w[nxt][0] = PW2[(size_t)((16 + w * 2 + 0) * 8 + ks3 + 1) * 64 + l];
                b2w[nxt][1] = PW2[(size_t)((16 + w * 2 + 1) * 8 + ks3 + 1) * 64 + l];
            }
            short8 af0 = *(const short8*)(LB + 16384 + ((0 * 8 + ks3) << 10) + loff);
            short8 af1 = *(const short8*)(LB + 16384 + ((1 * 8 + ks3) << 10) + loff);
            __builtin_amdgcn_s_setprio(1);
            acc[0][0] = __builtin_amdgcn_mfma_f32_16x16x32_bf16(af0, b2w[cur][0], acc[0][0], 0, 0, 0);
            acc[0][1] = __builtin_amdgcn_mfma_f32_16x16x32_bf16(af0, b2w[cur][1], acc[0][1], 0, 0, 0);
            acc[1][0] = __builtin_amdgcn_mfma_f32_16x16x32_bf16(af1, b2w[cur][0], acc[1][0], 0, 0, 0);
            acc[1][1] = __builtin_amdgcn_mfma_f32_16x16x32_bf16(af1, b2w[cur][1], acc[1][1], 0, 0, 0);
            __builtin_amdgcn_s_setprio(0);
        }
#pragma unroll
        for (int cf = 0; cf < 2; cf++) {
            float bsv = b2[256 + (w << 5) + (cf << 4) + l15];
#pragma unroll
            for (int g = 0; g < 2; g++)
#pragma unroll
                for (int j = 0; j < 4; j++)
                    svd[cf][g][j] = (acc[g][cf][j] + bsv) * dotv[cf][g][j];
        }
    }
    {   // ss (sg=0)
        b2w[0][0] = PW2[(size_t)((0 + w * 2 + 0) * 8) * 64 + l];
        b2w[0][1] = PW2[(size_t)((0 + w * 2 + 1) * 8) * 64 + l];
        floatx4 acc[2][2];
#pragma unroll
        for (int g = 0; g < 2; g++) { acc[g][0] = (floatx4)0.f; acc[g][1] = (floatx4)0.f; }
#pragma unroll
        for (int ks3 = 0; ks3 < 8; ks3++) {
            int cur = ks3 & 1, nxt = cur ^ 1;
            if (ks3 < 7) {
                b2w[nxt][0] = PW2[(size_t)((w * 2 + 0) * 8 + ks3 + 1) * 64 + l];
                b2w[nxt][1] = PW2[(size_t)((w * 2 + 1) * 8 + ks3 + 1) * 64 + l];
            }
            short8 af0 = *(const short8*)(LB + 16384 + ((0 * 8 + ks3) << 10) + loff);
            short8 af1 = *(const short8*)(LB + 16384 + ((1 * 8 + ks3) << 10) + loff);
            __builtin_amdgcn_s_setprio(1);
            acc[0][0] = __builtin_amdgcn_mfma_f32_16x16x32_bf16(af0, b2w[cur][0], acc[0][0], 0, 0, 0);
            acc[0][1] = __builtin_amdgcn_mfma_f32_16x16x32_bf16(af0, b2w[cur][1], acc[0][1], 0, 0, 0);
            acc[1][0] = __builtin_amdgcn_mfma_f32_16x16x32_bf16(af1, b2w[cur][0], acc[1][0], 0, 0, 0);
            acc[1][1] = __builtin_amdgcn_mfma_f32_16x16x32_bf16(af1, b2w[cur][1], acc[1][1], 0, 0, 0);
            __builtin_amdgcn_s_setprio(0);
        }
        // sdelta = (ss+bss) + sv*dot -> slotX [a][c] (norm frags dead since B4)
#pragma unroll
        for (int cf = 0; cf < 2; cf++) {
            int c = (w << 5) + (cf << 4) + l15;
            float bss = b2[c];
#pragma unroll
            for (int g = 0; g < 2; g++)
#pragma unroll
                for (int j = 0; j < 4; j++) {
                    int a = (g << 4) + (lhi << 2) + j;
                    float sd = (acc[g][cf][j] + bss) + svd[cf][g][j];
                    int bo = ((a << 9) + (c << 1)) ^ ((a & 7) << 4);
                    *(unsigned short*)(LB + bo) = f2bf(sd);
                }
        }
    }
    {   // vv (sg=2) -> a_vv kept in regs (svd reused)
        b2w[0][0] = PW2[(size_t)((32 + w * 2 + 0) * 8) * 64 + l];
        b2w[0][1] = PW2[(size_t)((32 + w * 2 + 1) * 8) * 64 + l];
        floatx4 acc[2][2];
#pragma unroll
        for (int g = 0; g < 2; g++) { acc[g][0] = (floatx4)0.f; acc[g][1] = (floatx4)0.f; }
#pragma unroll
        for (int ks3 = 0; ks3 < 8; ks3++) {
            int cur = ks3 & 1, nxt = cur ^ 1;
            if (ks3 < 7) {
                b2w[nxt][0] = PW2[(size_t)((32 + w * 2 + 0) * 8 + ks3 + 1) * 64 + l];
                b2w[nxt][1] = PW2[(size_t)((32 + w * 2 + 1) * 8 + ks3 + 1) * 64 + l];
            }
            short8 af0 = *(const short8*)(LB + 16384 + ((0 * 8 + ks3) << 10) + loff);
            short8 af1 = *(const short8*)(LB + 16384 + ((1 * 8 + ks3) << 10) + loff);
            __builtin_amdgcn_s_setprio(1);
            acc[0][0] = __builtin_amdgcn_mfma_f32_16x16x32_bf16(af0, b2w[cur][0], acc[0][0], 0, 0, 0);
            acc[0][1] = __builtin_amdgcn_mfma_f32_16x16x32_bf16(af0, b2w[cur][1], acc[0][1], 0, 0, 0);
            acc[1][0] = __builtin_amdgcn_mfma_f32_16x16x32_bf16(af1, b2w[cur][0], acc[1][0], 0, 0, 0);
            acc[1][1] = __builtin_amdgcn_mfma_f32_16x16x32_bf16(af1, b2w[cur][1], acc[1][1], 0, 0, 0);
            __builtin_amdgcn_s_setprio(0);
        }
#pragma unroll
        for (int cf = 0; cf < 2; cf++) {
            float bvv = b2[512 + (w << 5) + (cf << 4) + l15];
#pragma unroll
            for (int g = 0; g < 2; g++)
#pragma unroll
                for (int j = 0; j < 4; j++)
                    svd[cf][g][j] = acc[g][cf][j] + bvv;
        }
    }

    BAR();  // B5: sdelta visible

    // ---- epilogue: s_out (LN map; raw s from regs; 256B contiguous) ----
    {
        size_t gb = (size_t)(atom0 + aLN) * H;
        int xo = (aLN & 7) << 4;
#pragma unroll
        for (int i = 0; i < 4; i++) {
            int chunk = lg + (i << 4);
            short4v sd4 = *(const short4v*)(LB + (((aLN << 9) + (chunk << 3)) ^ xo));
            floatx4 o;
#pragma unroll
            for (int j = 0; j < 4; j++) o[j] = bf2f((unsigned short)srp[i][j]) + bf2f((unsigned short)sd4[j]);
            *(floatx4*)(s_out + gb + chunk * 4) = o;
        }
    }

    // ---- epilogue: v_out = v + a_vv * Uv (acc map; v re-read, L2-warm) ----
#pragma unroll
    for (int cf = 0; cf < 2; cf++) {
        int c = (w << 5) + (cf << 4) + l15;
#pragma unroll
        for (int g = 0; g < 2; g++)
#pragma unroll
            for (int j = 0; j < 4; j++) {
                int a = (g << 4) + (lhi << 2) + j;
                size_t base = (size_t)(atom0 + a) * 3 * H + c;
                float av = svd[cf][g][j];
#pragma unroll
                for (int d = 0; d < 3; d++) {
                    float uv = upk(uvh[cf][d][g][j >> 1], j & 1);
                    size_t vi = base + (size_t)d * H;
                    v_out[vi] = v[vi] + av * uv;
                }
            }
    }
}

extern "C" void kernel_launch(void* const* d_in, const int* in_sizes, int n_in,
                              void* d_out, int out_size, void* d_ws, size_t ws_size,
                              hipStream_t stream) {
    const float* s     = (const float*)d_in[0];
    const float* v     = (const float*)d_in[1];
    const float* gamma = (const float*)d_in[2];
    const float* beta  = (const float*)d_in[3];
    const float* U_W   = (const float*)d_in[4];
    const float* V_W   = (const float*)d_in[5];
    const float* W1    = (const float*)d_in[6];
    const float* b1    = (const float*)d_in[7];
    const float* W2    = (const float*)d_in[8];
    const float* b2    = (const float*)d_in[9];
    float* s_out = (float*)d_out;
    float* v_out = s_out + (size_t)NATOMS * H;
    unsigned short* P = (unsigned short*)d_ws;   // needs 917504 B

    pack_weights<<<dim3(224), dim3(256), 0, stream>>>(U_W, V_W, W1, W2, P);
    painn_main<<<dim3(NBLK), dim3(512), 0, stream>>>(s, v, gamma, beta, b1, b2, P, s_out, v_out);
}